// Round 11
// baseline (151.192 us; speedup 1.0000x reference)
//
#include <hip/hip_runtime.h>

// SpikeEncoder: embedding gather + LayerNorm + LIF scan in FLOAT64
// (harness 'np' reference is f64 — confirmed round 3).
// B=8, S=2048, V=57344, D=1536. Outputs: [spikes (B*S*D), x (B*S*D)] fp32.
//
// Round 11: spec was random-gather-HBM-bound (256B slices of random emb rows,
// ~2.5 TB/s effective — matches the ~65 µs). ln_stats now also emits a 16-bit
// residual lo s.t. hi(f32 x output) + lo reconstructs x_f64 to 40 bits.
// spec/fixup STREAM hi+lo sequentially (L3-resident, coalesced, no tok/LDS/
// barrier). Spike-flip risk vs f64 ref ~1e-4 (40-bit x'); spec/fixup share
// the decode so the entry-state equality check remains exact.

constexpr int Bv = 8, Sv = 2048, Dv = 1536;
constexpr int Cn = 32;              // chunks over S
constexpr int Ln = Sv / Cn;         // 64 steps per chunk
constexpr int Wn = 64;              // warmup steps (merge horizon — keep!)
constexpr int BD = Bv * Dv;         // 12288 chains

// ws layout
constexpr size_t FLAG_OFF  = 0;
constexpr size_t STATS_OFF = 64;                                   // 2*B*S doubles
constexpr size_t SE_OFF    = STATS_OFF + (size_t)2 * Bv * Sv * 8;  // {start,end} double2
constexpr size_t LO_OFF    = SE_OFF + (size_t)Cn * BD * 16;        // int16 residuals
constexpr size_t WS_NEED   = LO_OFF + (size_t)Bv * Sv * Dv * 2;    // ~57 MB total

// ---- bit-exact step function (identical expression tree everywhere) ----
__device__ __forceinline__ double lif_step(double v, double x, bool& spike) {
#pragma clang fp contract(off)
    double vv = v * 0.95;            // separate mul (np rounding)
    vv = vv + x;                     // separate add
    vv = fmin(fmax(vv, -3.0), 3.0);
    spike = (vv >= 1.0);
    return spike ? 0.0 : vv;
}
__device__ __forceinline__ double ln_x64(float e, double mu, double rs,
                                         double gd, double bd) {
#pragma clang fp contract(off)
    return (((double)e - mu) * rs) * gd + bd;
}

// ---- hi/lo16 codec: x' = hi + q * 2^-16 * ulp(hi); 40-bit mantissa ----
__device__ __forceinline__ short encode_lo(double x64, float hi) {
    unsigned u = __float_as_uint(hi);
    unsigned e = (u >> 23) & 0xFFu;
    if (e <= 23u) return 0;                      // |hi| denormal-ish: lo irrelevant
    const double inv_ulp = (double)__uint_as_float((277u - e) << 23);  // 2^(150-e)
    double s = (x64 - (double)hi) * inv_ulp * 65536.0;   // in [-32768, 32768]
    int q = __double2int_rn(s);
    q = (q > 32767) ? 32767 : q;
    return (short)q;
}
__device__ __forceinline__ double decode_x(float hi, short q) {
    unsigned u = __float_as_uint(hi);
    unsigned e = (u >> 23) & 0xFFu;
    unsigned ef = (e > 24u) ? (e - 23u) : 1u;    // guard; q==0 when e<=23
    const double ulp = (double)__uint_as_float(ef << 23);   // 2^(e-150)
    return (double)hi + (double)q * (ulp * (1.0 / 65536.0));
}

// ---------------------------------------------------------------------------
// Kernel 0: detect int64 vs int32 token buffer (tokens < 2^31 => int64 data
// has ALL odd int32 words zero). flag = shift (1 for int64, 0 for int32).
// ---------------------------------------------------------------------------
extern "C" __global__ __launch_bounds__(1024)
void detect_tok64(const int* __restrict__ tok, int* __restrict__ flag)
{
    __shared__ int any_nz;
    if (threadIdx.x == 0) any_nz = 0;
    __syncthreads();
    int nz = 0;
    for (int i = threadIdx.x; i < (Bv * Sv) / 2; i += 1024) nz |= tok[2 * i + 1];
    if (nz) atomicOr(&any_nz, 1);
    __syncthreads();
    if (threadIdx.x == 0) flag[0] = (any_nz == 0) ? 1 : 0;
}

// ---------------------------------------------------------------------------
// Kernel 1: per-row LN stats in f64 (one row per 128-thread block).
// Writes: stats {mu,rstd}, x (f32 output) = hi, and lo16 residuals to ws.
// ---------------------------------------------------------------------------
extern "C" __global__ __launch_bounds__(128)
void ln_stats_kernel(const int* __restrict__ tok,
                     const float* __restrict__ emb,
                     const float* __restrict__ gamma,
                     const float* __restrict__ beta,
                     float* __restrict__ x_out,
                     short* __restrict__ lo_out,
                     double* __restrict__ stats,
                     const int* __restrict__ tok64_flag)
{
#pragma clang fp contract(off)
    __shared__ double p1[2], p2[2];

    const int row = blockIdx.x;
    const int t   = threadIdx.x;
    const int lane = t & 63, wave = t >> 6;

    const int shift = tok64_flag[0];
    const long long tk = (long long)tok[(size_t)row << shift];
    const float* src = emb + tk * (long long)Dv;

    float4 xv[3];
#pragma unroll
    for (int k = 0; k < 3; ++k) xv[k] = reinterpret_cast<const float4*>(src)[t + 128 * k];

    double s = 0.0;
#pragma unroll
    for (int k = 0; k < 3; ++k) {
        s += (double)xv[k].x; s += (double)xv[k].y;
        s += (double)xv[k].z; s += (double)xv[k].w;
    }
#pragma unroll
    for (int off = 1; off < 64; off <<= 1) s += __shfl_xor(s, off);
    if (lane == 0) p1[wave] = s;
    __syncthreads();
    const double mu = (p1[0] + p1[1]) / 1536.0;

    double q = 0.0;
#pragma unroll
    for (int k = 0; k < 3; ++k) {
        double d0 = (double)xv[k].x - mu; q += d0 * d0;
        double d1 = (double)xv[k].y - mu; q += d1 * d1;
        double d2 = (double)xv[k].z - mu; q += d2 * d2;
        double d3 = (double)xv[k].w - mu; q += d3 * d3;
    }
#pragma unroll
    for (int off = 1; off < 64; off <<= 1) q += __shfl_xor(q, off);
    if (lane == 0) p2[wave] = q;
    __syncthreads();
    const double var  = (p2[0] + p2[1]) / 1536.0;
    const double rstd = 1.0 / sqrt(var + 1e-5);

    if (t == 0) { stats[2 * row] = mu; stats[2 * row + 1] = rstd; }

    float* dst = x_out  + (long long)row * Dv;
    short* dlo = lo_out + (long long)row * Dv;
#pragma unroll
    for (int k = 0; k < 3; ++k) {
        const int f4 = t + 128 * k;
        const float4 g4 = reinterpret_cast<const float4*>(gamma)[f4];
        const float4 b4 = reinterpret_cast<const float4*>(beta)[f4];
        const double x0 = (((double)xv[k].x - mu) * rstd) * (double)g4.x + (double)b4.x;
        const double x1 = (((double)xv[k].y - mu) * rstd) * (double)g4.y + (double)b4.y;
        const double x2 = (((double)xv[k].z - mu) * rstd) * (double)g4.z + (double)b4.z;
        const double x3 = (((double)xv[k].w - mu) * rstd) * (double)g4.w + (double)b4.w;
        float4 o; o.x = (float)x0; o.y = (float)x1; o.z = (float)x2; o.w = (float)x3;
        short4 lo4;
        lo4.x = encode_lo(x0, o.x); lo4.y = encode_lo(x1, o.y);
        lo4.z = encode_lo(x2, o.z); lo4.w = encode_lo(x3, o.w);
        reinterpret_cast<float4*>(dst)[f4] = o;
        reinterpret_cast<short4*>(dlo)[f4] = lo4;
    }
}

// ---------------------------------------------------------------------------
// Kernel 2a: speculative LIF chunks — pure sequential streams of hi+lo.
// Grid = B * Cn * (D/256) = 1536 blocks x 256 (6144 waves, all resident).
// No LDS, no barrier, no gather.
// ---------------------------------------------------------------------------
extern "C" __global__ __launch_bounds__(256)
void lif64_spec(const float* __restrict__ xs,
                const short* __restrict__ lo,
                float* __restrict__ spk,
                double2* __restrict__ se)
{
    constexpr int DBLK = Dv / 256;            // 6
    const int t    = threadIdx.x;
    const int bid  = blockIdx.x;
    const int dblk = bid % DBLK;
    const int c    = (bid / DBLK) % Cn;
    const int b    = bid / (DBLK * Cn);
    const int d    = dblk * 256 + t;

    const int s0 = c * Ln;
    const int sw = (c == 0) ? 0 : s0 - Wn;
    const int TN = s0 + Ln - sw;              // 64 or 128
    const int warm = s0 - sw;                 // 0 or 64

    const size_t base = ((size_t)b * Sv + sw) * (size_t)Dv + d;
    const float* xp = xs  + base;
    const short* lp = lo  + base;
    float*       sp = spk + base;

    constexpr int U = 8;
    float h0[U], h1[U]; short q0[U], q1[U];
#pragma unroll
    for (int k = 0; k < U; ++k) { h0[k] = xp[k * Dv]; q0[k] = lp[k * Dv]; }

    double v = 0.0, vstart = 0.0;
    for (int i = 0; i < TN; i += U) {
        if (i + U < TN) {
#pragma unroll
            for (int k = 0; k < U; ++k) {
                h1[k] = xp[(i + U + k) * Dv];
                q1[k] = lp[(i + U + k) * Dv];
            }
        }
#pragma unroll
        for (int k = 0; k < U; ++k) {
            const int idx = i + k;
            if (idx == warm) vstart = v;
            const double x = decode_x(h0[k], q0[k]);
            bool spike;
            v = lif_step(v, x, spike);
            if (idx >= warm)
                __builtin_nontemporal_store(spike ? 1.0f : 0.0f,
                                            &sp[(size_t)idx * Dv]);
        }
#pragma unroll
        for (int k = 0; k < U; ++k) { h0[k] = h1[k]; q0[k] = q1[k]; }
    }

    const size_t chain = (size_t)b * Dv + d;
    double2 a; a.x = vstart; a.y = v;
    se[(size_t)c * BD + chain] = a;
}

// ---------------------------------------------------------------------------
// Chunk recompute for fixup (streams hi+lo, same decode as spec).
// ---------------------------------------------------------------------------
__device__ __forceinline__ double fix_chunk(const float* __restrict__ xp,
                                            const short* __restrict__ lp,
                                            float* __restrict__ sp, double v)
{
    constexpr int U = 8;
    float h0[U], h1[U]; short q0[U], q1[U];
#pragma unroll
    for (int k = 0; k < U; ++k) { h0[k] = xp[k * Dv]; q0[k] = lp[k * Dv]; }
    for (int i = 0; i < Ln; i += U) {
        if (i + U < Ln) {
#pragma unroll
            for (int k = 0; k < U; ++k) {
                h1[k] = xp[(i + U + k) * Dv];
                q1[k] = lp[(i + U + k) * Dv];
            }
        }
#pragma unroll
        for (int k = 0; k < U; ++k) {
            const double x = decode_x(h0[k], q0[k]);
            bool spike;
            v = lif_step(v, x, spike);
            sp[(size_t)(i + k) * Dv] = spike ? 1.0f : 0.0f;
        }
#pragma unroll
        for (int k = 0; k < U; ++k) { h0[k] = h1[k]; q0[k] = q1[k]; }
    }
    return v;
}

// ---------------------------------------------------------------------------
// Kernel 2b: exact fixup. One thread per chain; 4-deep rotating prefetch of
// the 32 {start,end} states (loads are address-independent); bitwise-equal
// entry => chunk exact, jump; else recompute via fix_chunk.
// ---------------------------------------------------------------------------
extern "C" __global__ __launch_bounds__(64)
void lif64_fixup(const float* __restrict__ xs,
                 const short* __restrict__ lo,
                 const double2* __restrict__ se,
                 float* __restrict__ spk)
{
    const int gid = blockIdx.x * 64 + threadIdx.x;   // chain id
    const int b = gid / Dv;
    const int d = gid - b * Dv;
    const size_t cb = (size_t)b * Sv * Dv + d;

    double2 buf[4], nbuf[4];
#pragma unroll
    for (int j = 0; j < 4; ++j) buf[j] = se[(size_t)j * BD + gid];

    double v = 0.0;
    for (int c4 = 0; c4 < Cn; c4 += 4) {
        if (c4 + 4 < Cn) {
#pragma unroll
            for (int j = 0; j < 4; ++j)
                nbuf[j] = se[(size_t)(c4 + 4 + j) * BD + gid];
        }
#pragma unroll
        for (int j = 0; j < 4; ++j) {
            const int c = c4 + j;
            if (v == buf[j].x) { v = buf[j].y; }
            else {
                const size_t off = cb + (size_t)(c * Ln) * Dv;
                v = fix_chunk(xs + off, lo + off, spk + off, v);
            }
        }
#pragma unroll
        for (int j = 0; j < 4; ++j) buf[j] = nbuf[j];
    }
}

// ---------------------------------------------------------------------------
// Fallback: sequential LIF, fully exact f64 path via emb gather (round-3
// proven). Used only if ws is too small for stats+se+lo arrays.
// ---------------------------------------------------------------------------
extern "C" __global__ __launch_bounds__(64)
void lif64_seq(const int* __restrict__ tok,
               const float* __restrict__ emb,
               const float* __restrict__ gamma,
               const float* __restrict__ beta,
               const double* __restrict__ stats,
               float* __restrict__ spk,
               const int* __restrict__ flags)
{
    const int gid = blockIdx.x * 64 + threadIdx.x;
    const int b = gid / Dv;
    const int d = gid - b * Dv;
    const int shift = flags[0];
    const int rowbase = b * Sv;
    const double gd = (double)gamma[d];
    const double bd = (double)beta[d];
    float* sp = spk + (size_t)b * Sv * Dv + d;

    constexpr int U = 8;
    float  ecur[U], enxt[U];
    double mcur[U], mnxt[U], rcur[U], rnxt[U];
#pragma unroll
    for (int k = 0; k < U; ++k) {
        const int row = rowbase + k;
        const long long tk = (long long)tok[(size_t)row << shift];
        ecur[k] = emb[tk * (long long)Dv + d];
        mcur[k] = stats[2 * row];
        rcur[k] = stats[2 * row + 1];
    }
    double v = 0.0;
    for (int s = 0; s < Sv; s += U) {
        if (s + U < Sv) {
#pragma unroll
            for (int k = 0; k < U; ++k) {
                const int row = rowbase + s + U + k;
                const long long tk = (long long)tok[(size_t)row << shift];
                enxt[k] = emb[tk * (long long)Dv + d];
                mnxt[k] = stats[2 * row];
                rnxt[k] = stats[2 * row + 1];
            }
        }
#pragma unroll
        for (int k = 0; k < U; ++k) {
            const double x = ln_x64(ecur[k], mcur[k], rcur[k], gd, bd);
            bool spike;
            v = lif_step(v, x, spike);
            __builtin_nontemporal_store(spike ? 1.0f : 0.0f, &sp[(size_t)(s + k) * Dv]);
        }
#pragma unroll
        for (int k = 0; k < U; ++k) { ecur[k] = enxt[k]; mcur[k] = mnxt[k]; rcur[k] = rnxt[k]; }
    }
}

extern "C" void kernel_launch(void* const* d_in, const int* in_sizes, int n_in,
                              void* d_out, int out_size, void* d_ws, size_t ws_size,
                              hipStream_t stream)
{
    const int*   tok   = (const int*)  d_in[0];
    const float* emb   = (const float*)d_in[1];
    const float* gamma = (const float*)d_in[2];
    const float* beta  = (const float*)d_in[3];

    float* out = (float*)d_out;
    float* spk = out;                               // output 0: spikes
    float* x   = out + (size_t)Bv * Sv * Dv;        // output 1: x (LN result)

    int*    flg   = (int*)((char*)d_ws + FLAG_OFF);
    double* stats = (double*)((char*)d_ws + STATS_OFF);

    detect_tok64<<<1, 1024, 0, stream>>>(tok, flg);

    if (ws_size >= WS_NEED) {
        double2* se  = (double2*)((char*)d_ws + SE_OFF);
        short*   lo  = (short*)((char*)d_ws + LO_OFF);
        ln_stats_kernel<<<Bv * Sv, 128, 0, stream>>>(
            tok, emb, gamma, beta, x, lo, stats, flg);
        lif64_spec<<<Bv * Cn * (Dv / 256), 256, 0, stream>>>(x, lo, spk, se);
        lif64_fixup<<<BD / 64, 64, 0, stream>>>(x, lo, se, spk);
    } else {
        // minimal-ws path: stats into ws head if it fits, else cannot run —
        // stats region (256 KB) is required; assume ws >= STATS_OFF + stats.
        short* lo_dummy = (short*)((char*)d_ws + STATS_OFF);  // unused
        ln_stats_kernel<<<Bv * Sv, 128, 0, stream>>>(
            tok, emb, gamma, beta, x, lo_dummy, stats, flg);  // lo overlaps stats? no:
        // fall back to exact sequential scan (doesn't use lo)
        lif64_seq<<<BD / 64, 64, 0, stream>>>(tok, emb, gamma, beta, stats, spk, flg);
    }
}

// Round 12
// 133.570 us; speedup vs baseline: 1.1319x; 1.1319x over previous
//
#include <hip/hip_runtime.h>

// SpikeEncoder: embedding gather + LayerNorm + LIF scan in FLOAT64
// (harness 'np' reference is f64 — confirmed round 3).
// B=8, S=2048, V=57344, D=1536. Outputs: [spikes (B*S*D), x (B*S*D)] fp32.
//
// Round 12: minimize total HBM bytes (R11 post-mortem: ~600 MB moved vs
// ~290 MB floor; unique emb rows ~86 MB => L3-resident after one pass).
//   ln_stats: stats ONLY (no x write) — pure gather pass, warms L3.
//   spec: fuses x-output — computes x64 from (e,mu,rs,g,b) with the exact
//         ln-epilogue expression (bitwise-identical f32 x), stores x+spike.
//         x is v-independent => always correct; fixup rewrites spikes only.
//   fixup: R9 gather recompute + 4-deep chunk-state prefetch.
// C=32 / W=64 unchanged (proven operating point).

constexpr int Bv = 8, Sv = 2048, Dv = 1536;
constexpr int Cn = 32;              // chunks over S
constexpr int Ln = Sv / Cn;         // 64 steps per chunk
constexpr int Wn = 64;              // warmup steps (merge horizon — keep!)
constexpr int BD = Bv * Dv;         // 12288 chains
constexpr int TNMAX = Ln + Wn;      // 128 rows max per chunk

// ws layout
constexpr size_t FLAG_OFF  = 0;
constexpr size_t STATS_OFF = 64;                                   // 2*B*S doubles
constexpr size_t SE_OFF    = STATS_OFF + (size_t)2 * Bv * Sv * 8;  // {start,end} double2
constexpr size_t WS_NEED   = SE_OFF + (size_t)Cn * BD * 16;        // ~6.5 MB

// ---- shared, bit-exact expression trees ----
__device__ __forceinline__ double ln_x64(float e, double mu, double rs,
                                         double gd, double bd) {
#pragma clang fp contract(off)
    return (((double)e - mu) * rs) * gd + bd;
}
__device__ __forceinline__ double lif_step(double v, double x, bool& spike) {
#pragma clang fp contract(off)
    double vv = v * 0.95;            // separate mul (np rounding)
    vv = vv + x;                     // separate add
    vv = fmin(fmax(vv, -3.0), 3.0);
    spike = (vv >= 1.0);
    return spike ? 0.0 : vv;
}

// ---------------------------------------------------------------------------
// Kernel 0: detect int64 vs int32 token buffer (tokens < 2^31 => int64 data
// has ALL odd int32 words zero). flag = shift (1 for int64, 0 for int32).
// ---------------------------------------------------------------------------
extern "C" __global__ __launch_bounds__(1024)
void detect_tok64(const int* __restrict__ tok, int* __restrict__ flag)
{
    __shared__ int any_nz;
    if (threadIdx.x == 0) any_nz = 0;
    __syncthreads();
    int nz = 0;
    for (int i = threadIdx.x; i < (Bv * Sv) / 2; i += 1024) nz |= tok[2 * i + 1];
    if (nz) atomicOr(&any_nz, 1);
    __syncthreads();
    if (threadIdx.x == 0) flag[0] = (any_nz == 0) ? 1 : 0;
}

// ---------------------------------------------------------------------------
// Kernel 1: per-row LN stats in f64 (one row per 128-thread block).
// STATS ONLY — no x write. Also warms L3 with every needed emb row.
// ---------------------------------------------------------------------------
extern "C" __global__ __launch_bounds__(128)
void ln_stats_kernel(const int* __restrict__ tok,
                     const float* __restrict__ emb,
                     double* __restrict__ stats,
                     const int* __restrict__ tok64_flag)
{
#pragma clang fp contract(off)
    __shared__ double p1[2], p2[2];

    const int row = blockIdx.x;
    const int t   = threadIdx.x;
    const int lane = t & 63, wave = t >> 6;

    const int shift = tok64_flag[0];
    const long long tk = (long long)tok[(size_t)row << shift];
    const float* src = emb + tk * (long long)Dv;

    float4 xv[3];
#pragma unroll
    for (int k = 0; k < 3; ++k) xv[k] = reinterpret_cast<const float4*>(src)[t + 128 * k];

    double s = 0.0;
#pragma unroll
    for (int k = 0; k < 3; ++k) {
        s += (double)xv[k].x; s += (double)xv[k].y;
        s += (double)xv[k].z; s += (double)xv[k].w;
    }
#pragma unroll
    for (int off = 1; off < 64; off <<= 1) s += __shfl_xor(s, off);
    if (lane == 0) p1[wave] = s;
    __syncthreads();
    const double mu = (p1[0] + p1[1]) / 1536.0;

    double q = 0.0;
#pragma unroll
    for (int k = 0; k < 3; ++k) {
        double d0 = (double)xv[k].x - mu; q += d0 * d0;
        double d1 = (double)xv[k].y - mu; q += d1 * d1;
        double d2 = (double)xv[k].z - mu; q += d2 * d2;
        double d3 = (double)xv[k].w - mu; q += d3 * d3;
    }
#pragma unroll
    for (int off = 1; off < 64; off <<= 1) q += __shfl_xor(q, off);
    if (lane == 0) p2[wave] = q;
    __syncthreads();
    const double var  = (p2[0] + p2[1]) / 1536.0;
    const double rstd = 1.0 / sqrt(var + 1e-5);

    if (t == 0) { stats[2 * row] = mu; stats[2 * row + 1] = rstd; }
}

// ---------------------------------------------------------------------------
// Kernel 2a: speculative LIF chunks + fused x-output.
// Grid = B * Cn * (D/256) = 1536 blocks x 256. LDS-staged row metadata;
// 8-deep prefetched emb gathers (L3-hot after ln pass). For owned indices,
// NT-stores x=(float)x64 (bitwise == old ln epilogue) and the spike.
// ---------------------------------------------------------------------------
extern "C" __global__ __launch_bounds__(256)
void lif64_spec(const int* __restrict__ tok,
                const float* __restrict__ emb,
                const float* __restrict__ gamma,
                const float* __restrict__ beta,
                const double* __restrict__ stats,
                float* __restrict__ x_out,
                float* __restrict__ spk,
                double2* __restrict__ se,
                const int* __restrict__ tok64_flag)
{
    constexpr int DBLK = Dv / 256;            // 6
    __shared__ int     tokl[TNMAX];
    __shared__ double2 statl[TNMAX];

    const int t    = threadIdx.x;
    const int bid  = blockIdx.x;
    const int dblk = bid % DBLK;
    const int c    = (bid / DBLK) % Cn;
    const int b    = bid / (DBLK * Cn);
    const int d    = dblk * 256 + t;

    const int s0 = c * Ln;
    const int sw = (c == 0) ? 0 : s0 - Wn;
    const int TN = s0 + Ln - sw;              // 64 or 128
    const int warm = s0 - sw;                 // 0 or 64
    const int rowbase = b * Sv;

    if (t < TN) {
        const int row = rowbase + sw + t;
        const int shift = tok64_flag[0];
        tokl[t]  = tok[(size_t)row << shift];                     // token (< 2^31)
        statl[t] = reinterpret_cast<const double2*>(stats)[row];  // {mu, rstd}
    }
    __syncthreads();

    const double gd = (double)gamma[d];
    const double bd = (double)beta[d];
    float* sp = spk   + (size_t)b * Sv * Dv + d;
    float* xo = x_out + (size_t)b * Sv * Dv + d;

    constexpr int U = 8;
    float ecur[U], enxt[U];
#pragma unroll
    for (int k = 0; k < U; ++k)
        ecur[k] = emb[(long long)tokl[k] * Dv + d];

    double v = 0.0, vstart = 0.0;
    for (int i = 0; i < TN; i += U) {
        if (i + U < TN) {
#pragma unroll
            for (int k = 0; k < U; ++k)
                enxt[k] = emb[(long long)tokl[i + U + k] * Dv + d];
        }
#pragma unroll
        for (int k = 0; k < U; ++k) {
            const int idx = i + k;
            if (idx == warm) vstart = v;
            const double2 st = statl[idx];
            const double x = ln_x64(ecur[k], st.x, st.y, gd, bd);
            bool spike;
            const double vn = lif_step(v, x, spike);
            if (idx >= warm) {
                const size_t off = (size_t)(sw + idx) * Dv;
                __builtin_nontemporal_store((float)x, &xo[off]);
                __builtin_nontemporal_store(spike ? 1.0f : 0.0f, &sp[off]);
            }
            v = vn;
        }
#pragma unroll
        for (int k = 0; k < U; ++k) ecur[k] = enxt[k];
    }

    const size_t chain = (size_t)b * Dv + d;
    double2 a; a.x = vstart; a.y = v;
    se[(size_t)c * BD + chain] = a;
}

// ---------------------------------------------------------------------------
// Kernel 2b: exact fixup. One thread per chain; 4-deep rotating prefetch of
// the 32 {start,end} states; bitwise-equal entry => chunk provably exact,
// jump via exit; else recompute the chunk's SPIKES (x already correct).
// ---------------------------------------------------------------------------
extern "C" __global__ __launch_bounds__(64)
void lif64_fixup(const int* __restrict__ tok,
                 const float* __restrict__ emb,
                 const float* __restrict__ gamma,
                 const float* __restrict__ beta,
                 const double* __restrict__ stats,
                 const double2* __restrict__ se,
                 float* __restrict__ spk,
                 const int* __restrict__ tok64_flag)
{
    const int gid = blockIdx.x * 64 + threadIdx.x;   // chain id
    const int b = gid / Dv;
    const int d = gid - b * Dv;
    const int shift = tok64_flag[0];
    const double gd = (double)gamma[d];
    const double bd = (double)beta[d];
    const int rowbase = b * Sv;
    float* sp = spk + (size_t)b * Sv * Dv + d;

    double2 buf[4], nbuf[4];
#pragma unroll
    for (int j = 0; j < 4; ++j) buf[j] = se[(size_t)j * BD + gid];

    double v = 0.0;
    for (int c4 = 0; c4 < Cn; c4 += 4) {
        if (c4 + 4 < Cn) {
#pragma unroll
            for (int j = 0; j < 4; ++j)
                nbuf[j] = se[(size_t)(c4 + 4 + j) * BD + gid];
        }
#pragma unroll
        for (int j = 0; j < 4; ++j) {
            const int c = c4 + j;
            if (v == buf[j].x) { v = buf[j].y; continue; }
            // recompute chunk c's spikes (rare): 8-deep prefetched gather
            constexpr int U = 8;
            const int s0 = c * Ln;
            float  ecur[U], enxt[U];
            double mcur[U], mnxt[U], rcur[U], rnxt[U];
#pragma unroll
            for (int k = 0; k < U; ++k) {
                const int row = rowbase + s0 + k;
                const long long tk = (long long)tok[(size_t)row << shift];
                ecur[k] = emb[tk * (long long)Dv + d];
                mcur[k] = stats[2 * row];
                rcur[k] = stats[2 * row + 1];
            }
            for (int i = 0; i < Ln; i += U) {
                if (i + U < Ln) {
#pragma unroll
                    for (int k = 0; k < U; ++k) {
                        const int row = rowbase + s0 + i + U + k;
                        const long long tk = (long long)tok[(size_t)row << shift];
                        enxt[k] = emb[tk * (long long)Dv + d];
                        mnxt[k] = stats[2 * row];
                        rnxt[k] = stats[2 * row + 1];
                    }
                }
#pragma unroll
                for (int k = 0; k < U; ++k) {
                    const double x = ln_x64(ecur[k], mcur[k], rcur[k], gd, bd);
                    bool spike;
                    v = lif_step(v, x, spike);
                    sp[(size_t)(s0 + i + k) * Dv] = spike ? 1.0f : 0.0f;
                }
#pragma unroll
                for (int k = 0; k < U; ++k) {
                    ecur[k] = enxt[k]; mcur[k] = mnxt[k]; rcur[k] = rnxt[k];
                }
            }
        }
#pragma unroll
        for (int j = 0; j < 4; ++j) buf[j] = nbuf[j];
    }
}

// ---------------------------------------------------------------------------
// Fallback: sequential LIF, exact f64 path, writes BOTH x and spikes.
// Used only if ws is too small for the chunk-state array (never in practice).
// ---------------------------------------------------------------------------
extern "C" __global__ __launch_bounds__(64)
void lif64_seq(const int* __restrict__ tok,
               const float* __restrict__ emb,
               const float* __restrict__ gamma,
               const float* __restrict__ beta,
               const double* __restrict__ stats,
               float* __restrict__ x_out,
               float* __restrict__ spk,
               const int* __restrict__ flags)
{
    const int gid = blockIdx.x * 64 + threadIdx.x;
    const int b = gid / Dv;
    const int d = gid - b * Dv;
    const int shift = flags[0];
    const int rowbase = b * Sv;
    const double gd = (double)gamma[d];
    const double bd = (double)beta[d];
    float* sp = spk   + (size_t)b * Sv * Dv + d;
    float* xo = x_out + (size_t)b * Sv * Dv + d;

    constexpr int U = 8;
    float  ecur[U], enxt[U];
    double mcur[U], mnxt[U], rcur[U], rnxt[U];
#pragma unroll
    for (int k = 0; k < U; ++k) {
        const int row = rowbase + k;
        const long long tk = (long long)tok[(size_t)row << shift];
        ecur[k] = emb[tk * (long long)Dv + d];
        mcur[k] = stats[2 * row];
        rcur[k] = stats[2 * row + 1];
    }
    double v = 0.0;
    for (int s = 0; s < Sv; s += U) {
        if (s + U < Sv) {
#pragma unroll
            for (int k = 0; k < U; ++k) {
                const int row = rowbase + s + U + k;
                const long long tk = (long long)tok[(size_t)row << shift];
                enxt[k] = emb[tk * (long long)Dv + d];
                mnxt[k] = stats[2 * row];
                rnxt[k] = stats[2 * row + 1];
            }
        }
#pragma unroll
        for (int k = 0; k < U; ++k) {
            const double x = ln_x64(ecur[k], mcur[k], rcur[k], gd, bd);
            bool spike;
            v = lif_step(v, x, spike);
            const size_t off = (size_t)(s + k) * Dv;
            __builtin_nontemporal_store((float)x, &xo[off]);
            __builtin_nontemporal_store(spike ? 1.0f : 0.0f, &sp[off]);
        }
#pragma unroll
        for (int k = 0; k < U; ++k) { ecur[k] = enxt[k]; mcur[k] = mnxt[k]; rcur[k] = rnxt[k]; }
    }
}

extern "C" void kernel_launch(void* const* d_in, const int* in_sizes, int n_in,
                              void* d_out, int out_size, void* d_ws, size_t ws_size,
                              hipStream_t stream)
{
    const int*   tok   = (const int*)  d_in[0];
    const float* emb   = (const float*)d_in[1];
    const float* gamma = (const float*)d_in[2];
    const float* beta  = (const float*)d_in[3];

    float* out = (float*)d_out;
    float* spk = out;                               // output 0: spikes
    float* x   = out + (size_t)Bv * Sv * Dv;        // output 1: x (LN result)

    int*    flg   = (int*)((char*)d_ws + FLAG_OFF);
    double* stats = (double*)((char*)d_ws + STATS_OFF);

    detect_tok64<<<1, 1024, 0, stream>>>(tok, flg);
    ln_stats_kernel<<<Bv * Sv, 128, 0, stream>>>(tok, emb, stats, flg);

    if (ws_size >= WS_NEED) {
        double2* se = (double2*)((char*)d_ws + SE_OFF);
        lif64_spec<<<Bv * Cn * (Dv / 256), 256, 0, stream>>>(
            tok, emb, gamma, beta, stats, x, spk, se, flg);
        lif64_fixup<<<BD / 64, 64, 0, stream>>>(
            tok, emb, gamma, beta, stats, se, spk, flg);
    } else {
        lif64_seq<<<BD / 64, 64, 0, stream>>>(
            tok, emb, gamma, beta, stats, x, spk, flg);
    }
}